// Round 3
// baseline (428.344 us; speedup 1.0000x reference)
//
#include <hip/hip_runtime.h>
#include <stdint.h>

typedef unsigned short u16;
typedef __bf16 bf16;
typedef bf16 bf16x8 __attribute__((ext_vector_type(8)));
typedef u16 u16x8 __attribute__((ext_vector_type(8)));
typedef float f32x4 __attribute__((ext_vector_type(4)));

__device__ __forceinline__ u16 f2bf(float f) {
  union { float f; unsigned u; } v; v.f = f;
  unsigned u = v.u;
  u += 0x7FFFu + ((u >> 16) & 1u);   // RNE (inputs are finite/well-scaled)
  return (u16)(u >> 16);
}

__device__ __forceinline__ bf16x8 as_bf16x8(u16x8 v) {
  return __builtin_bit_cast(bf16x8, v);
}

__device__ __forceinline__ f32x4 mfma16(bf16x8 a, bf16x8 b, f32x4 c) {
  return __builtin_amdgcn_mfma_f32_16x16x32_bf16(a, b, c, 0, 0, 0);
}

// ---------------------------------------------------------------------------
// Transpose + fp32->bf16 convert: src [R][256] f32 row-major ->
// dst[o*dstStride + dstOff + r] (bf16), o in [0,256)
// ---------------------------------------------------------------------------
__global__ __launch_bounds__(256) void k_transpose(const float* __restrict__ src,
    u16* __restrict__ dst, int R, long dstStride, long dstOff) {
  __shared__ float tile[64][65];
  const int t = threadIdx.x;
  const int tr = t >> 6, tc = t & 63;
  const long rb = (long)blockIdx.x * 64;
  const int ob = blockIdx.y * 64;
#pragma unroll
  for (int i = 0; i < 16; ++i) {
    int r = i * 4 + tr;
    tile[r][tc] = src[(rb + r) * 256 + ob + tc];
  }
  __syncthreads();
#pragma unroll
  for (int i = 0; i < 16; ++i) {
    int orow = i * 4 + tr;
    dst[(long)(ob + orow) * dstStride + dstOff + rb + tc] = f2bf(tile[tc][orow]);
  }
}

// ---------------------------------------------------------------------------
// Small MFMA GEMM: out[b][o] = act(A[b][:] @ WT[o][:]^T + bias[o])
// A rows come from A0 (k<256) / A1 (k>=256) when A1 != nullptr (cat mode).
// block 256 (4 waves), wave tile [16 b][64 o], grid.x = 4096/16.
// ---------------------------------------------------------------------------
__global__ __launch_bounds__(256) void k_gemm_small(const float* __restrict__ A0,
    const float* __restrict__ A1, int K, const u16* __restrict__ WT,
    const float* __restrict__ bias, float* __restrict__ out, int relu_flag) {
  const int t = threadIdx.x;
  const int wid = t >> 6, lane = t & 63;
  const int l15 = lane & 15, lhi = lane >> 4;
  const int b0 = blockIdx.x * 16;
  const int o0 = wid * 64;
  const long row = b0 + l15;
  const int kg = lhi * 8;
  f32x4 acc[4] = {};
  for (int ks = 0; ks < K; ks += 32) {
    int k = ks + kg;
    const float* ap = (A1 != nullptr && k >= 256) ? (A1 + row * 256 + (k - 256))
                                                  : (A0 + row * 256 + k);
    f32x4 f0 = *(const f32x4*)ap;
    f32x4 f1 = *(const f32x4*)(ap + 4);
    u16x8 a;
    a[0]=f2bf(f0[0]); a[1]=f2bf(f0[1]); a[2]=f2bf(f0[2]); a[3]=f2bf(f0[3]);
    a[4]=f2bf(f1[0]); a[5]=f2bf(f1[1]); a[6]=f2bf(f1[2]); a[7]=f2bf(f1[3]);
    bf16x8 av = as_bf16x8(a);
#pragma unroll
    for (int nf = 0; nf < 4; ++nf) {
      int o = o0 + nf * 16 + l15;
      u16x8 braw = *(const u16x8*)(WT + (long)o * K + k);
      acc[nf] = mfma16(av, as_bf16x8(braw), acc[nf]);
    }
  }
#pragma unroll
  for (int nf = 0; nf < 4; ++nf) {
    int o = o0 + nf * 16 + l15;
    float bs = bias[o];
#pragma unroll
    for (int r = 0; r < 4; ++r) {
      long b = b0 + lhi * 4 + r;
      float v = acc[nf][r] + bs;
      if (relu_flag) v = fmaxf(v, 0.f);
      out[b * 256 + o] = v;
    }
  }
}

// ---------------------------------------------------------------------------
// Big GEMM: out0^T[o][b] partials = sum_p W2T[o][p] * M[b][p],
//   M[b][p=k*256+i] = h21[b][k]*wgt12[b][i]  (k<256), = wgt12[b][i] (bias rows)
// block 512 (8 waves), tile [256 o][64 b], K-step 64, split-K=8 (chunk 7 gets
// the 256 bias rows). XOR-swizzled LDS, register-prefetch pipeline.
// ---------------------------------------------------------------------------
__global__ __launch_bounds__(512, 4) void k_big(const u16* __restrict__ W2T,
    const float* __restrict__ h21, const float* __restrict__ wgt12,
    float* __restrict__ partials) {
  __shared__ u16 ldsA[256 * 64];   // [o][slot] swizzled, 32KB
  __shared__ u16 ldsM[64 * 64];    // [b][slot] swizzled, 8KB
  const int t = threadIdx.x;
  const int wid = t >> 6, lane = t & 63;
  const int l15 = lane & 15, lhi = lane >> 4;
  const int b0 = blockIdx.x * 64;
  const int chunk = blockIdx.y;
  const int nsteps = (chunk == 7) ? 132 : 128;
  const long pc0 = (long)chunk * 8192;
  const int wo = (wid >> 1) * 64;
  const int wb = (wid & 1) * 32;
  const int trow = t >> 3;                 // 0..63
  const int tcg = t & 7;                   // content group
  const int tslot = tcg ^ (trow & 7);      // XOR swizzle slot
  const long hbase = (long)(b0 + trow) * 256;
  f32x4 acc[4][2] = {};

  u16x8 sa[4];
  f32x4 w0, w1;
  float scale;
  auto LOAD = [&](int ks) {
    const long p0 = pc0 + (long)ks * 64;
    const int kk = (int)(p0 >> 8);
    const int i0 = (int)(p0 & 255);
#pragma unroll
    for (int is = 0; is < 4; ++is)
      sa[is] = *(const u16x8*)(W2T + (long)(is * 64 + trow) * 65792 + p0 + tcg * 8);
    scale = 1.0f;
    if (kk < 256) scale = h21[hbase + kk];
    const float* wp = wgt12 + hbase + i0 + tcg * 8;
    w0 = *(const f32x4*)wp;
    w1 = *(const f32x4*)(wp + 4);
  };

  LOAD(0);
  for (int ks = 0; ks < nsteps; ++ks) {
    u16x8 mv;
    mv[0]=f2bf(scale*w0[0]); mv[1]=f2bf(scale*w0[1]);
    mv[2]=f2bf(scale*w0[2]); mv[3]=f2bf(scale*w0[3]);
    mv[4]=f2bf(scale*w1[0]); mv[5]=f2bf(scale*w1[1]);
    mv[6]=f2bf(scale*w1[2]); mv[7]=f2bf(scale*w1[3]);
    __syncthreads();
#pragma unroll
    for (int is = 0; is < 4; ++is)
      *(u16x8*)(ldsA + (is * 64 + trow) * 64 + tslot * 8) = sa[is];
    *(u16x8*)(ldsM + trow * 64 + tslot * 8) = mv;
    __syncthreads();
    if (ks + 1 < nsteps) LOAD(ks + 1);   // prefetch under compute
#pragma unroll
    for (int ksub = 0; ksub < 2; ++ksub) {
      const int g = ksub * 4 + lhi;
      bf16x8 af[4];
#pragma unroll
      for (int mf = 0; mf < 4; ++mf) {
        int o = wo + mf * 16 + l15;
        af[mf] = as_bf16x8(*(const u16x8*)(ldsA + o * 64 + ((g ^ (o & 7)) * 8)));
      }
      bf16x8 bv[2];
#pragma unroll
      for (int nf = 0; nf < 2; ++nf) {
        int b = wb + nf * 16 + l15;
        bv[nf] = as_bf16x8(*(const u16x8*)(ldsM + b * 64 + ((g ^ (b & 7)) * 8)));
      }
#pragma unroll
      for (int mf = 0; mf < 4; ++mf)
#pragma unroll
        for (int nf = 0; nf < 2; ++nf)
          acc[mf][nf] = mfma16(af[mf], bv[nf], acc[mf][nf]);
    }
  }
  const long cb = (long)chunk * (256L * 4096);
#pragma unroll
  for (int mf = 0; mf < 4; ++mf)
#pragma unroll
    for (int nf = 0; nf < 2; ++nf)
#pragma unroll
      for (int r = 0; r < 4; ++r) {
        int o = wo + mf * 16 + lhi * 4 + r;
        int bg = b0 + wb + nf * 16 + l15;
        partials[cb + (long)o * 4096 + bg] = acc[mf][nf][r];
      }
}

// ---------------------------------------------------------------------------
// Reduce split-K partials [8][256 o][4096 b] + LayerNorm + ReLU -> out1[b][o]
// block 256, tile 64 b x 256 o
// ---------------------------------------------------------------------------
__global__ __launch_bounds__(256) void k_lnbr(const float* __restrict__ partials,
    const float* __restrict__ g, const float* __restrict__ bb,
    float* __restrict__ out1) {
  __shared__ float tile[64][257];
  const int t = threadIdx.x;
  const int b0 = blockIdx.x * 64;
  const int bl = t & 63;
  const int og = t >> 6;
  for (int os = 0; os < 256; os += 4) {
    int o = os + og;
    long idx = (long)o * 4096 + b0 + bl;
    float s = 0.f;
#pragma unroll
    for (int c = 0; c < 8; ++c) s += partials[(long)c * (256L * 4096) + idx];
    tile[bl][o] = s;
  }
  __syncthreads();
  const int wid = t >> 6, lane = t & 63;
  for (int i = 0; i < 16; ++i) {
    int b = wid * 16 + i;
    float v0 = tile[b][lane * 4 + 0];
    float v1 = tile[b][lane * 4 + 1];
    float v2 = tile[b][lane * 4 + 2];
    float v3 = tile[b][lane * 4 + 3];
    float s1 = v0 + v1 + v2 + v3;
    float s2 = v0*v0 + v1*v1 + v2*v2 + v3*v3;
#pragma unroll
    for (int m = 1; m < 64; m <<= 1) {
      s1 += __shfl_xor(s1, m);
      s2 += __shfl_xor(s2, m);
    }
    float mean = s1 * (1.f / 256.f);
    float var = s2 * (1.f / 256.f) - mean * mean;
    float rstd = rsqrtf(var + 1e-5f);
    f32x4 o4;
    float vv[4] = {v0, v1, v2, v3};
#pragma unroll
    for (int j = 0; j < 4; ++j) {
      int o = lane * 4 + j;
      float x = (vv[j] - mean) * rstd * g[o] + bb[o];
      o4[j] = fmaxf(x, 0.f);
    }
    *(f32x4*)&out1[(long)(b0 + b) * 256 + lane * 4] = o4;
  }
}

// ---------------------------------------------------------------------------
// Final: out = relu(LN(A @ w3)) via MFMA + in-register LN.
// block 256 (4 waves), wave tile [16 b][256 o]; grid 64.
// ---------------------------------------------------------------------------
__global__ __launch_bounds__(256) void k_final(const float* __restrict__ A,
    const u16* __restrict__ WT, const float* __restrict__ g,
    const float* __restrict__ bb, float* __restrict__ out) {
  const int t = threadIdx.x;
  const int wid = t >> 6, lane = t & 63;
  const int l15 = lane & 15, lhi = lane >> 4;
  const int b0 = blockIdx.x * 64 + wid * 16;
  const long row = b0 + l15;
  const int kg = lhi * 8;
  f32x4 acc[16] = {};
  for (int ks = 0; ks < 256; ks += 32) {
    int k = ks + kg;
    const float* ap = A + row * 256 + k;
    f32x4 f0 = *(const f32x4*)ap;
    f32x4 f1 = *(const f32x4*)(ap + 4);
    u16x8 a;
    a[0]=f2bf(f0[0]); a[1]=f2bf(f0[1]); a[2]=f2bf(f0[2]); a[3]=f2bf(f0[3]);
    a[4]=f2bf(f1[0]); a[5]=f2bf(f1[1]); a[6]=f2bf(f1[2]); a[7]=f2bf(f1[3]);
    bf16x8 av = as_bf16x8(a);
#pragma unroll
    for (int nf = 0; nf < 16; ++nf) {
      int o = nf * 16 + l15;
      u16x8 braw = *(const u16x8*)(WT + (long)o * 256 + k);
      acc[nf] = mfma16(av, as_bf16x8(braw), acc[nf]);
    }
  }
#pragma unroll
  for (int r = 0; r < 4; ++r) {
    long b = b0 + lhi * 4 + r;
    float s1 = 0.f, s2 = 0.f;
#pragma unroll
    for (int nf = 0; nf < 16; ++nf) {
      float x = acc[nf][r];
      s1 += x; s2 += x * x;
    }
    s1 += __shfl_xor(s1, 1); s2 += __shfl_xor(s2, 1);
    s1 += __shfl_xor(s1, 2); s2 += __shfl_xor(s2, 2);
    s1 += __shfl_xor(s1, 4); s2 += __shfl_xor(s2, 4);
    s1 += __shfl_xor(s1, 8); s2 += __shfl_xor(s2, 8);
    float mean = s1 * (1.f / 256.f);
    float var = s2 * (1.f / 256.f) - mean * mean;
    float rstd = rsqrtf(var + 1e-5f);
#pragma unroll
    for (int nf = 0; nf < 16; ++nf) {
      int o = nf * 16 + l15;
      float v = (acc[nf][r] - mean) * rstd * g[o] + bb[o];
      out[b * 256 + o] = fmaxf(v, 0.f);
    }
  }
}

// ---------------------------------------------------------------------------
extern "C" void kernel_launch(void* const* d_in, const int* in_sizes, int n_in,
                              void* d_out, int out_size, void* d_ws, size_t ws_size,
                              hipStream_t stream) {
  const float* img = (const float*)d_in[0];
  const float* loc = (const float*)d_in[1];
  const float* w11 = (const float*)d_in[2];
  const float* b11 = (const float*)d_in[3];
  const float* w12 = (const float*)d_in[4];
  const float* b12 = (const float*)d_in[5];
  const float* w21 = (const float*)d_in[6];
  const float* b21 = (const float*)d_in[7];
  const float* w22 = (const float*)d_in[8];
  const float* b22 = (const float*)d_in[9];
  const float* lng = (const float*)d_in[10];
  const float* lnb = (const float*)d_in[11];
  const float* w3  = (const float*)d_in[12];
  const float* g3  = (const float*)d_in[13];
  const float* bb3 = (const float*)d_in[14];

  char* ws = (char*)d_ws;
  u16* W2T   = (u16*)(ws);                      // 256*65792*2 = 33,685,504
  u16* W11T  = (u16*)(ws + 33685504);           // 262,144
  u16* W21T  = (u16*)(ws + 33947648);           // 262,144
  u16* W12T  = (u16*)(ws + 34209792);           // 131,072
  u16* W3T   = (u16*)(ws + 34340864);           // 131,072
  float* h11   = (float*)(ws + 34471936);       // 4,194,304
  float* h21   = (float*)(ws + 38666240);       // 4,194,304
  float* wgt12 = (float*)(ws + 42860544);       // 4,194,304
  float* parts = (float*)(ws + 47054848);       // 33,554,432
  float* out1  = (float*)(ws + 80609280);       // 4,194,304  (end 84,803,584)
  float* outp  = (float*)d_out;

  // weight transposes (fp32 -> bf16, [K][256] -> [256][K])
  hipLaunchKernelGGL(k_transpose, dim3(1024, 4), dim3(256), 0, stream,
                     w22, W2T, 65536, (long)65792, (long)0);
  hipLaunchKernelGGL(k_transpose, dim3(4, 4), dim3(256), 0, stream,
                     b22, W2T, 256, (long)65792, (long)65536);
  hipLaunchKernelGGL(k_transpose, dim3(8, 4), dim3(256), 0, stream,
                     w11, W11T, 512, (long)512, (long)0);
  hipLaunchKernelGGL(k_transpose, dim3(8, 4), dim3(256), 0, stream,
                     w21, W21T, 512, (long)512, (long)0);
  hipLaunchKernelGGL(k_transpose, dim3(4, 4), dim3(256), 0, stream,
                     w12, W12T, 256, (long)256, (long)0);
  hipLaunchKernelGGL(k_transpose, dim3(4, 4), dim3(256), 0, stream,
                     w3, W3T, 256, (long)256, (long)0);

  // h11 = relu(cat@w11+b11), h21 = relu(cat@w21+b21), wgt12 = h11@w12+b12
  hipLaunchKernelGGL(k_gemm_small, dim3(256), dim3(256), 0, stream,
                     img, loc, 512, W11T, b11, h11, 1);
  hipLaunchKernelGGL(k_gemm_small, dim3(256), dim3(256), 0, stream,
                     img, loc, 512, W21T, b21, h21, 1);
  hipLaunchKernelGGL(k_gemm_small, dim3(256), dim3(256), 0, stream,
                     h11, (const float*)nullptr, 256, W12T, b12, wgt12, 0);

  // big fused hypernet GEMM (split-K partials)
  hipLaunchKernelGGL(k_big, dim3(64, 8), dim3(512), 0, stream,
                     W2T, h21, wgt12, parts);

  // reduce + LN + relu
  hipLaunchKernelGGL(k_lnbr, dim3(64), dim3(256), 0, stream, parts, lng, lnb, out1);

  // final GEMM + LN + relu -> first half of d_out
  hipLaunchKernelGGL(k_final, dim3(64), dim3(256), 0, stream, out1, W3T, g3, bb3, outp);

  // second output: loc_fea passthrough
  hipMemcpyAsync(outp + 1048576, loc, 4194304, hipMemcpyDeviceToDevice, stream);
}

// Round 4
// 425.304 us; speedup vs baseline: 1.0071x; 1.0071x over previous
//
#include <hip/hip_runtime.h>
#include <stdint.h>

typedef unsigned short u16;
typedef __bf16 bf16;
typedef bf16 bf16x8 __attribute__((ext_vector_type(8)));
typedef u16 u16x8 __attribute__((ext_vector_type(8)));
typedef float f32x4 __attribute__((ext_vector_type(4)));

__device__ __forceinline__ u16 f2bf(float f) {
  union { float f; unsigned u; } v; v.f = f;
  unsigned u = v.u;
  u += 0x7FFFu + ((u >> 16) & 1u);   // RNE
  return (u16)(u >> 16);
}

__device__ __forceinline__ bf16x8 as_bf16x8(u16x8 v) {
  return __builtin_bit_cast(bf16x8, v);
}

__device__ __forceinline__ f32x4 mfma16(bf16x8 a, bf16x8 b, f32x4 c) {
  return __builtin_amdgcn_mfma_f32_16x16x32_bf16(a, b, c, 0, 0, 0);
}

#define AS1 __attribute__((address_space(1)))
#define AS3 __attribute__((address_space(3)))
// async global->LDS, 16B/lane; LDS dest = uniform base + lane*16
__device__ __forceinline__ void gl_lds16(const u16* g, u16* l) {
  __builtin_amdgcn_global_load_lds((const AS1 void*)g, (AS3 void*)l, 16, 0, 0);
}

// ---------------------------------------------------------------------------
// w22 transpose + cvt: src [R][256] f32 -> dst[o][r] bf16  (16B stores)
// ---------------------------------------------------------------------------
__global__ __launch_bounds__(256) void k_transpose(const float* __restrict__ src,
    u16* __restrict__ dst, long dstStride, long dstOff) {
  __shared__ float tile[64][65];
  const int t = threadIdx.x;
  const int tr = t >> 6, tc = t & 63;
  const long rb = (long)blockIdx.x * 64;
  const int ob = blockIdx.y * 64;
#pragma unroll
  for (int i = 0; i < 16; ++i) {
    int r = i * 4 + tr;
    tile[r][tc] = src[(rb + r) * 256 + ob + tc];
  }
  __syncthreads();
  const int orow = t >> 2, seg = t & 3;
#pragma unroll
  for (int h = 0; h < 2; ++h) {
    u16x8 v;
#pragma unroll
    for (int j = 0; j < 8; ++j) v[j] = f2bf(tile[seg * 16 + h * 8 + j][orow]);
    *(u16x8*)&dst[(long)(ob + orow) * dstStride + dstOff + rb + seg * 16 + h * 8] = v;
  }
}

// ---------------------------------------------------------------------------
// 5 small transposes merged: grid (28, 4)
// ---------------------------------------------------------------------------
__global__ __launch_bounds__(256) void k_transpose_multi(
    const float* __restrict__ b22, const float* __restrict__ w11,
    const float* __restrict__ w21, const float* __restrict__ w12,
    const float* __restrict__ w3, u16* __restrict__ W2T, u16* __restrict__ W11T,
    u16* __restrict__ W21T, u16* __restrict__ W12T, u16* __restrict__ W3T) {
  __shared__ float tile[64][65];
  const int x = blockIdx.x;
  const float* src; u16* dst; long stride, off; int rb;
  if (x < 4)       { src = b22; dst = W2T;  stride = 65792; off = 65536; rb = x; }
  else if (x < 12) { src = w11; dst = W11T; stride = 512;   off = 0;     rb = x - 4; }
  else if (x < 20) { src = w21; dst = W21T; stride = 512;   off = 0;     rb = x - 12; }
  else if (x < 24) { src = w12; dst = W12T; stride = 256;   off = 0;     rb = x - 20; }
  else             { src = w3;  dst = W3T;  stride = 256;   off = 0;     rb = x - 24; }
  const long rbase = (long)rb * 64;
  const int t = threadIdx.x;
  const int tr = t >> 6, tc = t & 63;
  const int ob = blockIdx.y * 64;
#pragma unroll
  for (int i = 0; i < 16; ++i) {
    int r = i * 4 + tr;
    tile[r][tc] = src[(rbase + r) * 256 + ob + tc];
  }
  __syncthreads();
  const int orow = t >> 2, seg = t & 3;
#pragma unroll
  for (int h = 0; h < 2; ++h) {
    u16x8 v;
#pragma unroll
    for (int j = 0; j < 8; ++j) v[j] = f2bf(tile[seg * 16 + h * 8 + j][orow]);
    *(u16x8*)&dst[(long)(ob + orow) * stride + off + rbase + seg * 16 + h * 8] = v;
  }
}

// ---------------------------------------------------------------------------
// Small MFMA GEMM body (shared): out[b][o] = act(A @ WT^T + bias)
// ---------------------------------------------------------------------------
__device__ __forceinline__ void gemm_small_body(const float* A0, const float* A1,
    int K, const u16* WT, const float* bias, float* out, int relu_flag) {
  const int t = threadIdx.x;
  const int wid = t >> 6, lane = t & 63;
  const int l15 = lane & 15, lhi = lane >> 4;
  const int b0 = blockIdx.x * 16;
  const int o0 = wid * 64;
  const long row = b0 + l15;
  const int kg = lhi * 8;
  f32x4 acc[4] = {};
  for (int ks = 0; ks < K; ks += 32) {
    int k = ks + kg;
    const float* ap = (A1 != nullptr && k >= 256) ? (A1 + row * 256 + (k - 256))
                                                  : (A0 + row * 256 + k);
    f32x4 f0 = *(const f32x4*)ap;
    f32x4 f1 = *(const f32x4*)(ap + 4);
    u16x8 a;
    a[0]=f2bf(f0[0]); a[1]=f2bf(f0[1]); a[2]=f2bf(f0[2]); a[3]=f2bf(f0[3]);
    a[4]=f2bf(f1[0]); a[5]=f2bf(f1[1]); a[6]=f2bf(f1[2]); a[7]=f2bf(f1[3]);
    bf16x8 av = as_bf16x8(a);
#pragma unroll
    for (int nf = 0; nf < 4; ++nf) {
      int o = o0 + nf * 16 + l15;
      u16x8 braw = *(const u16x8*)(WT + (long)o * K + k);
      acc[nf] = mfma16(av, as_bf16x8(braw), acc[nf]);
    }
  }
#pragma unroll
  for (int nf = 0; nf < 4; ++nf) {
    int o = o0 + nf * 16 + l15;
    float bs = bias[o];
#pragma unroll
    for (int r = 0; r < 4; ++r) {
      long b = b0 + lhi * 4 + r;
      float v = acc[nf][r] + bs;
      if (relu_flag) v = fmaxf(v, 0.f);
      out[b * 256 + o] = v;
    }
  }
}

__global__ __launch_bounds__(256) void k_gemm_pair(const float* __restrict__ img,
    const float* __restrict__ loc, const u16* __restrict__ W11T,
    const float* __restrict__ b11, float* __restrict__ h11,
    const u16* __restrict__ W21T, const float* __restrict__ b21,
    float* __restrict__ h21) {
  if (blockIdx.y == 0) gemm_small_body(img, loc, 512, W11T, b11, h11, 1);
  else                 gemm_small_body(img, loc, 512, W21T, b21, h21, 1);
}

__global__ __launch_bounds__(256) void k_gemm_small(const float* __restrict__ A0,
    const u16* __restrict__ WT, const float* __restrict__ bias,
    float* __restrict__ out) {
  gemm_small_body(A0, nullptr, 256, WT, bias, out, 0);
}

// ---------------------------------------------------------------------------
// Big GEMM: partials[chunk][o][b] = sum_p W2T[o][p] * M[b][p]
//   M[b][p=k*256+i] = h21[b][k]*wgt12[b][i] (k<256), = wgt12[b][i] (bias rows)
// tile [128 o][128 b], 8 waves (2o x 4b), K-step 64, split-K 8.
// Double-buffered A (global_load_lds w16, source-permuted) + M (reg->ds_write),
// ONE barrier per step, 2-deep M-reg prefetch, setprio around MFMA.
// ---------------------------------------------------------------------------
__global__ __launch_bounds__(512, 4) void k_big(const u16* __restrict__ W2T,
    const float* __restrict__ h21, const float* __restrict__ wgt12,
    float* __restrict__ partials) {
  __shared__ u16 ldsA[2][128 * 64];   // [o-row][8 slots of 8 u16], 16KB each
  __shared__ u16 ldsM[2][128 * 64];   // [b-row][8 slots], 16KB each
  const int t = threadIdx.x;
  const int wid = t >> 6, lane = t & 63;
  const int l15 = lane & 15, lhi = lane >> 4;
  const int xb = blockIdx.x;               // 0..63
  const int o_base = (xb & 1) * 128;
  const int b0 = (xb >> 1) * 128;
  const int chunk = blockIdx.y;
  const int nsteps = (chunk == 7) ? 132 : 128;
  const int wo = (wid >> 2) * 64;
  const int wb = (wid & 3) * 32;
  // staging ids
  const int rb = t >> 2;                   // M row 0..127
  const int sp = t & 3;                    // slot pair
  const int arow_in = lane >> 3;           // row within 8-row gload region
  const int aslot = lane & 7;
  f32x4 acc[4][2] = {};

  auto LOADM = [&](int ks, f32x4& W0, f32x4& W1, f32x4& W2, f32x4& W3, float& SC) {
    const int p0 = chunk * 8192 + ks * 64;
    const int kk = p0 >> 8;
    const int i0 = p0 & 255;
    const float* wp = wgt12 + (long)(b0 + rb) * 256 + i0 + sp * 16;
    W0 = *(const f32x4*)wp;  W1 = *(const f32x4*)(wp + 4);
    W2 = *(const f32x4*)(wp + 8); W3 = *(const f32x4*)(wp + 12);
    SC = (kk < 256) ? h21[(long)(b0 + rb) * 256 + kk] : 1.0f;
  };

  auto STAGE = [&](int ks, int buf, const f32x4& W0, const f32x4& W1,
                   const f32x4& W2, const f32x4& W3, float SC) {
    const int p0 = chunk * 8192 + ks * 64;
    {  // A: 2 wave-issues of 1KB each (rows (j*8+wid)*8 .. +8)
      const int r0 = wid * 8 + arow_in;
      gl_lds16(W2T + (long)(o_base + r0) * 65792 + p0 + ((aslot ^ (r0 & 7)) * 8),
               &ldsA[buf][wid * 512]);
      const int r1 = (8 + wid) * 8 + arow_in;
      gl_lds16(W2T + (long)(o_base + r1) * 65792 + p0 + ((aslot ^ (r1 & 7)) * 8),
               &ldsA[buf][(8 + wid) * 512]);
    }
    {  // M: convert + 2 swizzled ds_write_b128
      u16x8 m0, m1;
      m0[0]=f2bf(SC*W0[0]); m0[1]=f2bf(SC*W0[1]); m0[2]=f2bf(SC*W0[2]); m0[3]=f2bf(SC*W0[3]);
      m0[4]=f2bf(SC*W1[0]); m0[5]=f2bf(SC*W1[1]); m0[6]=f2bf(SC*W1[2]); m0[7]=f2bf(SC*W1[3]);
      m1[0]=f2bf(SC*W2[0]); m1[1]=f2bf(SC*W2[1]); m1[2]=f2bf(SC*W2[2]); m1[3]=f2bf(SC*W2[3]);
      m1[4]=f2bf(SC*W3[0]); m1[5]=f2bf(SC*W3[1]); m1[6]=f2bf(SC*W3[2]); m1[7]=f2bf(SC*W3[3]);
      const int s0 = sp * 2;
      *(u16x8*)&ldsM[buf][rb * 64 + ((s0 ^ (rb & 7)) * 8)] = m0;
      *(u16x8*)&ldsM[buf][rb * 64 + (((s0 + 1) ^ (rb & 7)) * 8)] = m1;
    }
  };

  auto MFMAPH = [&](int buf) {
#pragma unroll
    for (int ksub = 0; ksub < 2; ++ksub) {
      const int g = ksub * 4 + lhi;
      bf16x8 af[4]; bf16x8 bv[2];
#pragma unroll
      for (int mf = 0; mf < 4; ++mf) {
        int ro = wo + mf * 16 + l15;
        af[mf] = as_bf16x8(*(const u16x8*)&ldsA[buf][ro * 64 + ((g ^ (ro & 7)) * 8)]);
      }
#pragma unroll
      for (int nf = 0; nf < 2; ++nf) {
        int rbb = wb + nf * 16 + l15;
        bv[nf] = as_bf16x8(*(const u16x8*)&ldsM[buf][rbb * 64 + ((g ^ (rbb & 7)) * 8)]);
      }
      __builtin_amdgcn_s_setprio(1);
#pragma unroll
      for (int mf = 0; mf < 4; ++mf)
#pragma unroll
        for (int nf = 0; nf < 2; ++nf)
          acc[mf][nf] = mfma16(af[mf], bv[nf], acc[mf][nf]);
      __builtin_amdgcn_s_setprio(0);
    }
  };

  f32x4 a0, a1, a2, a3, c0, c1, c2, c3; float sa, sc;
  LOADM(0, a0, a1, a2, a3, sa);
  STAGE(0, 0, a0, a1, a2, a3, sa);
  LOADM(1, c0, c1, c2, c3, sc);
  __syncthreads();                       // step 0 buffers ready

  for (int s = 0; s < nsteps; s += 2) {
    // even step: reads buf0, stages buf1
    STAGE(s + 1, 1, c0, c1, c2, c3, sc);
    if (s + 2 < nsteps) LOADM(s + 2, a0, a1, a2, a3, sa);
    MFMAPH(0);
    __syncthreads();
    // odd step: reads buf1, stages buf0
    if (s + 2 < nsteps) STAGE(s + 2, 0, a0, a1, a2, a3, sa);
    if (s + 3 < nsteps) LOADM(s + 3, c0, c1, c2, c3, sc);
    MFMAPH(1);
    __syncthreads();
  }

  const long cb = (long)chunk * (256L * 4096);
#pragma unroll
  for (int mf = 0; mf < 4; ++mf)
#pragma unroll
    for (int nf = 0; nf < 2; ++nf)
#pragma unroll
      for (int r = 0; r < 4; ++r) {
        int o = o_base + wo + mf * 16 + lhi * 4 + r;
        int bg = b0 + wb + nf * 16 + l15;
        partials[cb + (long)o * 4096 + bg] = acc[mf][nf][r];
      }
}

// ---------------------------------------------------------------------------
// Fused tail: reduce split-K partials + LN + ReLU -> bf16 LDS tile ->
// MFMA GEMM with w3 + LN + ReLU -> out. grid 256, block 256 (16 b-rows).
// ---------------------------------------------------------------------------
__global__ __launch_bounds__(256) void k_tail(const float* __restrict__ parts,
    const float* __restrict__ lng, const float* __restrict__ lnb,
    const u16* __restrict__ W3T, const float* __restrict__ g3,
    const float* __restrict__ bb3, float* __restrict__ out) {
  __shared__ float tile[16][260];
  __shared__ u16 A16[16][264];
  __shared__ float s1s[4][16], s2s[4][16];
  __shared__ float mz[16], rz[16];
  const int t = threadIdx.x;
  const int b0 = blockIdx.x * 16;
  // ---- phase 1: reduce 8 chunks -> tile[b][o]
  {
    const int oq = t >> 2, bseg = t & 3;
#pragma unroll
    for (int j = 0; j < 4; ++j) {
      const int o = oq + j * 64;
      f32x4 s = {};
#pragma unroll
      for (int c = 0; c < 8; ++c)
        s += *(const f32x4*)&parts[(long)c * (256L * 4096) + (long)o * 4096 + b0 + bseg * 4];
#pragma unroll
      for (int q = 0; q < 4; ++q) tile[bseg * 4 + q][o] = s[q];
    }
  }
  __syncthreads();
  // ---- LN #1 (per b-row, 16 threads/row) + ReLU + bf16 -> A16
  {
    const int r = t >> 4, og = t & 15;
    float v[16];
    float s1 = 0.f, s2 = 0.f;
#pragma unroll
    for (int q = 0; q < 16; ++q) {
      float x = tile[r][og * 16 + q];
      v[q] = x; s1 += x; s2 += x * x;
    }
    s1 += __shfl_xor(s1, 1); s2 += __shfl_xor(s2, 1);
    s1 += __shfl_xor(s1, 2); s2 += __shfl_xor(s2, 2);
    s1 += __shfl_xor(s1, 4); s2 += __shfl_xor(s2, 4);
    s1 += __shfl_xor(s1, 8); s2 += __shfl_xor(s2, 8);
    float mean = s1 * (1.f / 256.f);
    float var = s2 * (1.f / 256.f) - mean * mean;
    float rstd = rsqrtf(var + 1e-5f);
    u16x8 w0, w1;
#pragma unroll
    for (int q = 0; q < 16; ++q) {
      int o = og * 16 + q;
      float x = (v[q] - mean) * rstd * lng[o] + lnb[o];
      x = fmaxf(x, 0.f);
      if (q < 8) w0[q] = f2bf(x); else w1[q - 8] = f2bf(x);
    }
    *(u16x8*)&A16[r][og * 16] = w0;
    *(u16x8*)&A16[r][og * 16 + 8] = w1;
  }
  __syncthreads();
  // ---- phase 2: [16 b][256 k] @ W3T -> acc, wave o-range 64
  const int wid = t >> 6, lane = t & 63;
  const int l15 = lane & 15, lhi = lane >> 4;
  const int wo = wid * 64;
  f32x4 acc[4] = {};
  for (int ks = 0; ks < 256; ks += 32) {
    const int k = ks + lhi * 8;
    bf16x8 av = as_bf16x8(*(const u16x8*)&A16[l15][k]);
#pragma unroll
    for (int nf = 0; nf < 4; ++nf) {
      int o = wo + nf * 16 + l15;
      u16x8 braw = *(const u16x8*)(W3T + (long)o * 256 + k);
      acc[nf] = mfma16(av, as_bf16x8(braw), acc[nf]);
    }
  }
  // ---- LN #2: cross-wave (o split across 4 waves)
#pragma unroll
  for (int r = 0; r < 4; ++r) {
    float s1 = 0.f, s2 = 0.f;
#pragma unroll
    for (int nf = 0; nf < 4; ++nf) { float x = acc[nf][r]; s1 += x; s2 += x * x; }
    s1 += __shfl_xor(s1, 1); s2 += __shfl_xor(s2, 1);
    s1 += __shfl_xor(s1, 2); s2 += __shfl_xor(s2, 2);
    s1 += __shfl_xor(s1, 4); s2 += __shfl_xor(s2, 4);
    s1 += __shfl_xor(s1, 8); s2 += __shfl_xor(s2, 8);
    if (l15 == 0) { s1s[wid][lhi * 4 + r] = s1; s2s[wid][lhi * 4 + r] = s2; }
  }
  __syncthreads();
  if (t < 16) {
    float s1 = s1s[0][t] + s1s[1][t] + s1s[2][t] + s1s[3][t];
    float s2 = s2s[0][t] + s2s[1][t] + s2s[2][t] + s2s[3][t];
    float mean = s1 * (1.f / 256.f);
    float var = s2 * (1.f / 256.f) - mean * mean;
    mz[t] = mean; rz[t] = rsqrtf(var + 1e-5f);
  }
  __syncthreads();
#pragma unroll
  for (int r = 0; r < 4; ++r) {
    const int b = lhi * 4 + r;
    const float mean = mz[b], rstd = rz[b];
#pragma unroll
    for (int nf = 0; nf < 4; ++nf) {
      int o = wo + nf * 16 + l15;
      float x = (acc[nf][r] - mean) * rstd * g3[o] + bb3[o];
      out[(long)(b0 + b) * 256 + o] = fmaxf(x, 0.f);
    }
  }
}

// ---------------------------------------------------------------------------
extern "C" void kernel_launch(void* const* d_in, const int* in_sizes, int n_in,
                              void* d_out, int out_size, void* d_ws, size_t ws_size,
                              hipStream_t stream) {
  const float* img = (const float*)d_in[0];
  const float* loc = (const float*)d_in[1];
  const float* w11 = (const float*)d_in[2];
  const float* b11 = (const float*)d_in[3];
  const float* w12 = (const float*)d_in[4];
  const float* b12 = (const float*)d_in[5];
  const float* w21 = (const float*)d_in[6];
  const float* b21 = (const float*)d_in[7];
  const float* w22 = (const float*)d_in[8];
  const float* b22 = (const float*)d_in[9];
  const float* lng = (const float*)d_in[10];
  const float* lnb = (const float*)d_in[11];
  const float* w3  = (const float*)d_in[12];
  const float* g3  = (const float*)d_in[13];
  const float* bb3 = (const float*)d_in[14];

  char* ws = (char*)d_ws;
  u16* W2T   = (u16*)(ws);                      // 33,685,504
  u16* W11T  = (u16*)(ws + 33685504);           // 262,144
  u16* W21T  = (u16*)(ws + 33947648);           // 262,144
  u16* W12T  = (u16*)(ws + 34209792);           // 131,072
  u16* W3T   = (u16*)(ws + 34340864);           // 131,072
  float* h11   = (float*)(ws + 34471936);       // 4,194,304
  float* h21   = (float*)(ws + 38666240);       // 4,194,304
  float* wgt12 = (float*)(ws + 42860544);       // 4,194,304
  float* parts = (float*)(ws + 47054848);       // 33,554,432 (end 80,609,280)
  float* outp  = (float*)d_out;

  // passthrough output (independent) first
  hipMemcpyAsync(outp + 1048576, loc, 4194304, hipMemcpyDeviceToDevice, stream);

  // weight transposes (fp32 -> bf16)
  hipLaunchKernelGGL(k_transpose, dim3(1024, 4), dim3(256), 0, stream,
                     w22, W2T, (long)65792, (long)0);
  hipLaunchKernelGGL(k_transpose_multi, dim3(28, 4), dim3(256), 0, stream,
                     b22, w11, w21, w12, w3, W2T, W11T, W21T, W12T, W3T);

  // h11 = relu(cat@w11+b11), h21 = relu(cat@w21+b21)
  hipLaunchKernelGGL(k_gemm_pair, dim3(256, 2), dim3(256), 0, stream,
                     img, loc, W11T, b11, h11, W21T, b21, h21);
  // wgt12 = h11@w12+b12
  hipLaunchKernelGGL(k_gemm_small, dim3(256), dim3(256), 0, stream,
                     h11, W12T, b12, wgt12);

  // big fused hypernet GEMM (split-K partials)
  hipLaunchKernelGGL(k_big, dim3(64, 8), dim3(512), 0, stream,
                     W2T, h21, wgt12, parts);

  // fused reduce+LN+ReLU + final GEMM+LN+ReLU
  hipLaunchKernelGGL(k_tail, dim3(256), dim3(256), 0, stream,
                     parts, lng, lnb, W3T, g3, bb3, outp);
}